// Round 1
// baseline (406.590 us; speedup 1.0000x reference)
//
#include <hip/hip_runtime.h>
#include <hip/hip_bf16.h>
#include <stdint.h>

// ---- problem constants ----
#define N_IMG 32
#define C_IN  256
#define HW    56
#define PIX   3136            // 56*56
#define M_TOT 100352          // 32*3136
#define C_OUT 256
#define K_TOT 2304            // 256*9
#define HP    58
#define WPAD  58
#define XPAD_ELEMS 27557888   // 32*58*58*256
#define OUT_IMG_STRIDE 802816 // 256*3136

// ---- GEMM tile config (m97-style) ----
#define BM 128
#define BN 128
#define BK 32
#define KT_ITERS 72           // 2304/32

typedef __attribute__((ext_vector_type(8))) short bf16x8_t;   // 8 bf16 = 4 VGPRs
typedef __attribute__((ext_vector_type(4))) float f32x4_t;

// ---------------- pass 0: zero-fill x_pad (borders must be 0; ws is poisoned) ----------
__global__ void zero_kernel(uint4* __restrict__ p, int n) {
    int i = blockIdx.x * 256 + threadIdx.x;
    if (i < n) p[i] = make_uint4(0u, 0u, 0u, 0u);
}

// ---------------- pass 1: NCHW fp32 -> padded NHWC bf16 transpose --------------------
// grid: 32 n * 4 ctile * 49 ptile = 6272 blocks, 256 threads
__global__ void xform_kernel(const float* __restrict__ x, __hip_bfloat16* __restrict__ xpad) {
    __shared__ float tile[64][65];
    int b   = blockIdx.x;
    int n   = b / 196;
    int rem = b - n * 196;
    int ct  = rem / 49;
    int pt  = rem - ct * 49;
    int c0 = ct * 64, p0 = pt * 64;
    int t = threadIdx.x;

    const float* xs = x + (size_t)n * C_IN * PIX;
    int pc = t & 63, cr = t >> 6;   // read phase: coalesced along pixels
#pragma unroll
    for (int it = 0; it < 16; ++it) {
        int c = c0 + it * 4 + cr;
        tile[it * 4 + cr][pc] = xs[(size_t)c * PIX + p0 + pc];
    }
    __syncthreads();
    int cl = t & 63, pr = t >> 6;   // write phase: coalesced along channels
#pragma unroll
    for (int it = 0; it < 16; ++it) {
        int p = p0 + it * 4 + pr;
        int h = p / HW, w = p - h * HW;
        float v = tile[cl][it * 4 + pr];
        xpad[(((size_t)n * HP + (h + 1)) * WPAD + (w + 1)) * C_IN + c0 + cl] = __float2bfloat16(v);
    }
}

// ---------------- pass 2: binarize + transpose weights -> wt[cout][tap][c] bf16 -------
__global__ void wxform_kernel(const float* __restrict__ w, __hip_bfloat16* __restrict__ wt) {
    int i = blockIdx.x * 256 + threadIdx.x;   // over 589824
    if (i >= C_OUT * K_TOT) return;
    int cout = i / K_TOT;
    int r    = i - cout * K_TOT;
    int tap  = r >> 8;
    int c    = r & 255;
    float v = w[cout * 2304 + c * 9 + tap];   // [cout][cin][3][3]
    float s = (v > 0.f) ? 1.f : ((v < 0.f) ? -1.f : 0.f);
    wt[i] = __float2bfloat16(s);
}

// ---------------- pass 3: implicit-GEMM MFMA conv ------------------------------------
__device__ __forceinline__ void gload_lds16(const __hip_bfloat16* g, __hip_bfloat16* l) {
    __builtin_amdgcn_global_load_lds(
        (const __attribute__((address_space(1))) void*)g,
        (__attribute__((address_space(3))) void*)l, 16, 0, 0);
}

__global__ void __launch_bounds__(256)
gemm_kernel(const __hip_bfloat16* __restrict__ xpad,
            const __hip_bfloat16* __restrict__ wt,
            const float* __restrict__ bias,
            float* __restrict__ out) {
    __shared__ __hip_bfloat16 As[BM * BK];   // [m][k], 32 bf16 per row
    __shared__ __hip_bfloat16 Bs[BN * BK];   // [n][k]

    int bx = blockIdx.x;
    int nt = bx & 1, mt = bx >> 1;
    int m0 = mt * BM, n0 = nt * BN;
    int tid  = threadIdx.x;
    int lane = tid & 63, wid = tid >> 6;
    int wm = wid >> 1, wn = wid & 1;

    // staging lane mapping: lane -> (row = lane>>2, k-offset = (lane&3)*8)
    int l4 = lane >> 2;
    int lk = (lane & 3) * 8;

    // A: per-lane base address of tap (0,0) for its two staged rows
    long Pq[2];
#pragma unroll
    for (int q = 0; q < 2; ++q) {
        int m = m0 + q * 64 + wid * 16 + l4;
        int nimg = m / PIX;
        int pix  = m - nimg * PIX;
        int h = pix / HW, w = pix - h * HW;
        // padded coords for tap (kh,kw) are (h+kh, w+kw); this is kh=kw=0 base
        Pq[q] = (((long)nimg * HP + h) * WPAD + w) * C_IN;
    }
    // B: per-lane base into wt
    long Wq[2];
#pragma unroll
    for (int q = 0; q < 2; ++q) {
        int n = n0 + q * 64 + wid * 16 + l4;
        Wq[q] = (long)n * K_TOT + lk;
    }

    f32x4_t acc[4][4] = {};

    // wave-uniform LDS staging bases (chunk q covers rows [q*64 + wid*16, +16))
    __hip_bfloat16* AsW0 = &As[wid * 512];
    __hip_bfloat16* AsW1 = &As[2048 + wid * 512];
    __hip_bfloat16* BsW0 = &Bs[wid * 512];
    __hip_bfloat16* BsW1 = &Bs[2048 + wid * 512];

    int ar = lane & 15;
    int kk = (lane >> 4) * 8;

    for (int kt = 0; kt < KT_ITERS; ++kt) {
        int k0  = kt * BK;
        int tap = k0 >> 8;                       // uniform: BK=32 chunk never crosses a tap
        int kh = tap / 3, kw = tap - kh * 3;
        int toff = (kh * WPAD + kw) * C_IN;
        int cofs = (k0 & 255) + lk;

        gload_lds16(xpad + Pq[0] + toff + cofs, AsW0);
        gload_lds16(xpad + Pq[1] + toff + cofs, AsW1);
        gload_lds16(wt + Wq[0] + k0, BsW0);
        gload_lds16(wt + Wq[1] + k0, BsW1);
        __syncthreads();

        bf16x8_t a[4], b[4];
#pragma unroll
        for (int i = 0; i < 4; ++i)
            a[i] = *(const bf16x8_t*)&As[(wm * 64 + i * 16 + ar) * BK + kk];
#pragma unroll
        for (int j = 0; j < 4; ++j)
            b[j] = *(const bf16x8_t*)&Bs[(wn * 64 + j * 16 + ar) * BK + kk];
#pragma unroll
        for (int i = 0; i < 4; ++i)
#pragma unroll
            for (int j = 0; j < 4; ++j)
                acc[i][j] = __builtin_amdgcn_mfma_f32_16x16x32_bf16(a[i], b[j], acc[i][j], 0, 0, 0);
        __syncthreads();
    }

    // epilogue: C/D layout col=lane&15 (n), row=(lane>>4)*4+reg (m)  [m89-verified]
    int cn = lane & 15;
    int rq = (lane >> 4) * 4;
#pragma unroll
    for (int i = 0; i < 4; ++i) {
        int mbase = m0 + wm * 64 + i * 16 + rq;
        long obase[4];
#pragma unroll
        for (int r = 0; r < 4; ++r) {
            int m = mbase + r;
            int nimg = m / PIX;
            int pix  = m - nimg * PIX;
            obase[r] = (long)nimg * OUT_IMG_STRIDE + pix;
        }
#pragma unroll
        for (int j = 0; j < 4; ++j) {
            int cout = n0 + wn * 64 + j * 16 + cn;
            float bv = bias[cout];
            long cof = (long)cout * PIX;
#pragma unroll
            for (int r = 0; r < 4; ++r)
                out[obase[r] + cof] = acc[i][j][r] + bv;
        }
    }
}

extern "C" void kernel_launch(void* const* d_in, const int* in_sizes, int n_in,
                              void* d_out, int out_size, void* d_ws, size_t ws_size,
                              hipStream_t stream) {
    const float* x    = (const float*)d_in[0];
    const float* wgt  = (const float*)d_in[1];
    const float* bias = (const float*)d_in[2];
    float* out = (float*)d_out;

    // workspace layout
    __hip_bfloat16* xpad = (__hip_bfloat16*)d_ws;                       // 55,115,776 B
    __hip_bfloat16* wt   = (__hip_bfloat16*)((char*)d_ws + 55115776);   // 1,179,648 B

    // pass 0: zero x_pad (ws is re-poisoned before every call)
    int n16 = XPAD_ELEMS * 2 / 16;               // 3,444,736
    zero_kernel<<<dim3((n16 + 255) / 256), dim3(256), 0, stream>>>((uint4*)xpad, n16);

    // pass 1: NCHW fp32 -> padded NHWC bf16
    xform_kernel<<<dim3(N_IMG * 4 * 49), dim3(256), 0, stream>>>(x, xpad);

    // pass 2: binarize weights -> wt[cout][tap][c]
    wxform_kernel<<<dim3((C_OUT * K_TOT + 255) / 256), dim3(256), 0, stream>>>(wgt, wt);

    // pass 3: implicit GEMM  (784 M-tiles × 2 N-tiles)
    gemm_kernel<<<dim3((M_TOT / BM) * (C_OUT / BN)), dim3(256), 0, stream>>>(xpad, wt, bias, out);
}

// Round 2
// 350.423 us; speedup vs baseline: 1.1603x; 1.1603x over previous
//
#include <hip/hip_runtime.h>
#include <hip/hip_bf16.h>
#include <stdint.h>

// ---- problem constants ----
#define N_IMG 32
#define C_IN  256
#define HW    56
#define PIX   3136            // 56*56
#define M_TOT 100352          // 32*3136
#define C_OUT 256
#define K_TOT 2304            // 256*9
#define HP    58
#define WPAD  58
#define XPAD_ELEMS 27557888   // 32*58*58*256
#define OUT_IMG_STRIDE 802816 // 256*3136

// ---- GEMM tile config: BM=224 (4 image rows), BN=128, slab-reuse over 9 taps ----
#define BM 224
#define BN 128
#define SLAB_PIX 348          // 6 padded rows * 58 cols
#define SLAB_STRIDE 40        // 32 chans + 8 pad elems (80 B: conflict-friendlier than 64 B)

typedef __attribute__((ext_vector_type(8))) short bf16x8_t;   // 8 bf16 = 4 VGPRs
typedef __attribute__((ext_vector_type(4))) float f32x4_t;

// ---------------- pass 0: zero only the padded border (3.7 MB, not 55 MB) -----------
__global__ void border_zero_kernel(__hip_bfloat16* __restrict__ xpad) {
    int t = blockIdx.x * 256 + threadIdx.x;   // 32 n * 228 border px * 32 uint4 = 233472
    if (t >= 32 * 228 * 32) return;
    int n = t / (228 * 32);
    int r = t - n * (228 * 32);
    int px = r >> 5, part = r & 31;
    int hp, wp;
    if (px < 58)       { hp = 0;  wp = px; }
    else if (px < 116) { hp = 57; wp = px - 116 + 58; }
    else { int k = px - 116; hp = 1 + (k >> 1); wp = (k & 1) ? 57 : 0; }
    long e = (((long)n * HP + hp) * WPAD + wp) * C_IN + part * 8;
    *(uint4*)(xpad + e) = make_uint4(0u, 0u, 0u, 0u);
}

// ---------------- pass 1: NCHW fp32 -> padded NHWC bf16 transpose --------------------
__global__ void xform_kernel(const float* __restrict__ x, __hip_bfloat16* __restrict__ xpad) {
    __shared__ float tile[64][65];
    int b   = blockIdx.x;
    int n   = b / 196;
    int rem = b - n * 196;
    int ct  = rem / 49;
    int pt  = rem - ct * 49;
    int c0 = ct * 64, p0 = pt * 64;
    int t = threadIdx.x;

    const float* xs = x + (size_t)n * C_IN * PIX;
    int pc = t & 63, cr = t >> 6;   // read: coalesced along pixels
#pragma unroll
    for (int it = 0; it < 16; ++it) {
        int c = c0 + it * 4 + cr;
        tile[it * 4 + cr][pc] = xs[(size_t)c * PIX + p0 + pc];
    }
    __syncthreads();
    int cl = t & 63, pr = t >> 6;   // write: coalesced along channels
#pragma unroll
    for (int it = 0; it < 16; ++it) {
        int p = p0 + it * 4 + pr;
        int h = p / HW, w = p - h * HW;
        float v = tile[cl][it * 4 + pr];
        xpad[(((size_t)n * HP + (h + 1)) * WPAD + (w + 1)) * C_IN + c0 + cl] = __float2bfloat16(v);
    }
}

// ---------------- pass 2: binarize + transpose weights -> wt[cout][tap][c] bf16 -------
__global__ void wxform_kernel(const float* __restrict__ w, __hip_bfloat16* __restrict__ wt) {
    int i = blockIdx.x * 256 + threadIdx.x;   // over 589824
    if (i >= C_OUT * K_TOT) return;
    int cout = i / K_TOT;
    int r    = i - cout * K_TOT;
    int tap  = r >> 8;
    int c    = r & 255;
    float v = w[cout * 2304 + c * 9 + tap];   // [cout][cin][3][3]
    float s = (v > 0.f) ? 1.f : ((v < 0.f) ? -1.f : 0.f);
    wt[i] = __float2bfloat16(s);
}

// ---------------- pass 3: slab-reuse implicit-GEMM MFMA conv -------------------------
// Block = 224 pixels (4 full image rows) x 128 couts. Per 32-chan chunk: stage a
// 6-row x 58-col x 32-chan LDS slab once, then 9 taps x 28 MFMA/wave with B
// fragments loaded global->VGPR (L2-hot, no barrier dependency). 252 MFMA per
// barrier pair vs 16 in the m97 structure.
__global__ void __launch_bounds__(256, 2)
gemm_kernel(const __hip_bfloat16* __restrict__ xpad,
            const __hip_bfloat16* __restrict__ wt,
            const float* __restrict__ bias,
            float* __restrict__ out) {
    __shared__ __hip_bfloat16 slab[SLAB_PIX * SLAB_STRIDE];   // 27840 B

    // XCD-pair swizzle: blocks bx and bx+8 share an XCD (bx%8); give them the
    // same M-tile (both N-tiles) so the A window is fetched once per XCD L2.
    int bx = blockIdx.x;                 // 896 blocks = 56 supergroups of 16
    int g = bx >> 4, xg = bx & 7, nt = (bx >> 3) & 1;
    int mt = g * 8 + xg;                 // 0..447
    int nimg = mt / 14, ti = mt - nimg * 14;
    int r0 = ti * 4;                     // first output row of this tile
    int n0 = nt * BN;

    int tid = threadIdx.x, lane = tid & 63, wid = tid >> 6;
    int wm = wid >> 1, wn = wid & 1;
    int ar = lane & 15;
    int kq = lane >> 4;                  // 0..3
    int kk = kq * 8;

    // per-lane a-frag slab byte offsets for tap (0,0): m = wm*112 + i*16 + ar
    int ppb[7];
#pragma unroll
    for (int i = 0; i < 7; ++i) {
        int m = wm * 112 + i * 16 + ar;
        int dr = m / 56, wcol = m - dr * 56;
        ppb[i] = (dr * 58 + wcol) * (SLAB_STRIDE * 2) + kq * 16;
    }
    // per-lane B bases (elems into wt)
    long wb[4];
#pragma unroll
    for (int j = 0; j < 4; ++j) {
        int n = n0 + wn * 64 + j * 16 + ar;
        wb[j] = (long)n * K_TOT + kk;
    }

    // the 6-row padded window is contiguous in xpad memory
    const __hip_bfloat16* srcBase = xpad + ((long)(nimg * HP + r0) * WPAD) * C_IN;

    f32x4_t acc[7][4] = {};

    for (int ch = 0; ch < 8; ++ch) {
        if (ch) __syncthreads();
        // stage slab: 348 px * 4 x 16B parts = 1392 slots, 256 threads x 6 iters
#pragma unroll
        for (int it = 0; it < 6; ++it) {
            int s = it * 256 + tid;
            if (s < SLAB_PIX * 4) {
                int pp = s >> 2, part = s & 3;
                uint4 v = *(const uint4*)(srcBase + (long)pp * C_IN + ch * 32 + part * 8);
                *(uint4*)((char*)slab + pp * (SLAB_STRIDE * 2) + part * 16) = v;
            }
        }
        __syncthreads();

#pragma unroll
        for (int t = 0; t < 9; ++t) {
            const int kh = t / 3, kw = t - kh * 3;
            const int toff = (kh * 58 + kw) * (SLAB_STRIDE * 2);
            bf16x8_t b[4];
#pragma unroll
            for (int j = 0; j < 4; ++j)
                b[j] = *(const bf16x8_t*)&wt[wb[j] + t * 256 + ch * 32];
            bf16x8_t a[7];
#pragma unroll
            for (int i = 0; i < 7; ++i)
                a[i] = *(const bf16x8_t*)((const char*)slab + ppb[i] + toff);
#pragma unroll
            for (int i = 0; i < 7; ++i)
#pragma unroll
                for (int j = 0; j < 4; ++j)
                    acc[i][j] = __builtin_amdgcn_mfma_f32_16x16x32_bf16(a[i], b[j], acc[i][j], 0, 0, 0);
        }
    }

    // epilogue: C/D col=lane&15 (n), row=(lane>>4)*4+reg (m); m-consecutive regs
    // -> float4 stores (16B-aligned: rq multiple of 4)
    int cn = lane & 15;
    int rq = (lane >> 4) * 4;
    long outb = (long)nimg * OUT_IMG_STRIDE + r0 * 56;
#pragma unroll
    for (int i = 0; i < 7; ++i) {
        int mb = wm * 112 + i * 16 + rq;
#pragma unroll
        for (int j = 0; j < 4; ++j) {
            int cout = n0 + wn * 64 + j * 16 + cn;
            float bv = bias[cout];
            f32x4_t v = acc[i][j];
            v[0] += bv; v[1] += bv; v[2] += bv; v[3] += bv;
            *(f32x4_t*)&out[outb + (long)cout * PIX + mb] = v;
        }
    }
}

extern "C" void kernel_launch(void* const* d_in, const int* in_sizes, int n_in,
                              void* d_out, int out_size, void* d_ws, size_t ws_size,
                              hipStream_t stream) {
    const float* x    = (const float*)d_in[0];
    const float* wgt  = (const float*)d_in[1];
    const float* bias = (const float*)d_in[2];
    float* out = (float*)d_out;

    __hip_bfloat16* xpad = (__hip_bfloat16*)d_ws;                       // 55,115,776 B
    __hip_bfloat16* wt   = (__hip_bfloat16*)((char*)d_ws + 55115776);   // 1,179,648 B

    // pass 0: zero only the padded border (ws is re-poisoned before every call)
    border_zero_kernel<<<dim3((32 * 228 * 32 + 255) / 256), dim3(256), 0, stream>>>(xpad);

    // pass 1: NCHW fp32 -> padded NHWC bf16
    xform_kernel<<<dim3(N_IMG * 4 * 49), dim3(256), 0, stream>>>(x, xpad);

    // pass 2: binarize weights -> wt[cout][tap][c]
    wxform_kernel<<<dim3((C_OUT * K_TOT + 255) / 256), dim3(256), 0, stream>>>(wgt, wt);

    // pass 3: slab-reuse implicit GEMM (448 M-tiles x 2 N-tiles, XCD-pair swizzled)
    gemm_kernel<<<dim3((M_TOT / BM) * (C_OUT / BN)), dim3(256), 0, stream>>>(xpad, wt, bias, out);
}